// Round 2
// baseline (860.755 us; speedup 1.0000x reference)
//
#include <hip/hip_runtime.h>

#define BSZ   16
#define LSEQ  8192
#define DMDL  64
#define DSD   32
#define HDD   32
#define NHD   4
#define DIN   128
#define NLAY  2
#define NOUTC 6
#define DPRJ  324
#define QC    64
#define NCH   128   // LSEQ/QC

// ---- device-global scratch (module-load allocated; no d_ws dependency) ----
__device__ float g_h0[BSZ*LSEQ*DMDL];       //  8388608 floats
__device__ float g_za[BSZ*LSEQ*DIN];        // 16777216
__device__ float g_xy[BSZ*LSEQ*DIN];        // 16777216  (xa, then reused in-place as y_intra)
__device__ float g_Ba[BSZ*LSEQ*DSD];        //  4194304
__device__ float g_Ca[BSZ*LSEQ*DSD];        //  4194304
__device__ float g_dt[BSZ*LSEQ*NHD];        //   524288
__device__ float g_pc[BSZ*LSEQ*NHD];        //   524288
__device__ float g_cS[BSZ*NCH*NHD*HDD*DSD]; //  8388608  (chunkS, scanned in-place into H_in)
__device__ float g_cL[BSZ*NCH*NHD];         //     8192
__device__ float g_pp[BSZ*16*DMDL];         //    16384
// total ~239 MB

__device__ __forceinline__ float silu_f(float v){ return v / (1.0f + __expf(-v)); }
__device__ __forceinline__ float softplus_f(float v){ return (v > 15.0f) ? v : __logf(1.0f + __expf(v)); }

// ---------------- linear_in: h0 = x @ W_in + b_in ----------------
__global__ __launch_bounds__(256) void k_linin(
    const float* __restrict__ x, const float* __restrict__ W,
    const float* __restrict__ bias)
{
  __shared__ float xs[64*60];   // [t][k] pad 60
  __shared__ float wl[57*64];   // [k][d]
  const int tid = threadIdx.x;
  const long tb = (long)blockIdx.x * 64;
  for (int i = tid; i < 64*57; i += 256){
    int t = i / 57, k = i - t*57;
    xs[t*60 + k] = x[tb*57 + i];
  }
  for (int i = tid; i < 57*64; i += 256) wl[i] = W[i];
  __syncthreads();
  const int t0 = (tid >> 4) * 4, d0 = (tid & 15) * 4;
  float acc[4][4];
  #pragma unroll
  for (int i = 0; i < 4; ++i)
    #pragma unroll
    for (int j = 0; j < 4; ++j) acc[i][j] = 0.f;
  for (int k = 0; k < 57; ++k){
    float4 w4 = *(const float4*)&wl[k*64 + d0];
    float wv[4] = {w4.x, w4.y, w4.z, w4.w};
    #pragma unroll
    for (int i = 0; i < 4; ++i){
      float xv = xs[(t0+i)*60 + k];
      #pragma unroll
      for (int j = 0; j < 4; ++j) acc[i][j] += xv * wv[j];
    }
  }
  float4 b4 = *(const float4*)&bias[d0];
  float bv[4] = {b4.x, b4.y, b4.z, b4.w};
  #pragma unroll
  for (int i = 0; i < 4; ++i){
    float4 o;
    o.x = acc[i][0] + bv[0]; o.y = acc[i][1] + bv[1];
    o.z = acc[i][2] + bv[2]; o.w = acc[i][3] + bv[3];
    *(float4*)&g_h0[(tb + t0 + i)*64 + d0] = o;
  }
}

// ---------------- in_proj GEMM + activations ----------------
__global__ __launch_bounds__(256) void k_proj(
    const float* __restrict__ W, const float* __restrict__ bias,
    const float* __restrict__ dt_bias, int l)
{
  __shared__ float hst[64*68];  // [k][t] transposed, pad 68
  __shared__ float Wt[64*68];   // [k][c]
  const int tid = threadIdx.x;
  const long tb = (long)blockIdx.x * 64;
  for (int i = tid; i < 4096; i += 256){
    int t = i >> 6, k = i & 63;
    hst[k*68 + t] = g_h0[(tb + t)*64 + k];
  }
  const float* Wl = W + (long)l * 64 * DPRJ;
  const float* bl = bias + (long)l * DPRJ;
  const int t0 = (tid >> 4) * 4, c0 = (tid & 15) * 4;
  for (int ct = 0; ct < 6; ++ct){
    const int cbase = ct * 64;
    const int cw = (ct == 5) ? 4 : 64;
    __syncthreads();
    for (int i = tid; i < 64 * cw; i += 256){
      int k = i / cw, cc = i - k * cw;
      Wt[k*68 + cc] = Wl[k*DPRJ + cbase + cc];
    }
    __syncthreads();
    if (c0 < cw){
      float acc[4][4];
      #pragma unroll
      for (int i = 0; i < 4; ++i)
        #pragma unroll
        for (int j = 0; j < 4; ++j) acc[i][j] = 0.f;
      for (int k = 0; k < 64; ++k){
        float4 h4 = *(const float4*)&hst[k*68 + t0];
        float4 w4 = *(const float4*)&Wt[k*68 + c0];
        float hv[4] = {h4.x, h4.y, h4.z, h4.w};
        float wv[4] = {w4.x, w4.y, w4.z, w4.w};
        #pragma unroll
        for (int i = 0; i < 4; ++i)
          #pragma unroll
          for (int j = 0; j < 4; ++j) acc[i][j] += hv[i] * wv[j];
      }
      const int gc0 = cbase + c0;
      float bv[4] = {bl[gc0], bl[gc0+1], bl[gc0+2], bl[gc0+3]};
      #pragma unroll
      for (int i = 0; i < 4; ++i){
        const long tok = tb + t0 + i;
        float v[4];
        #pragma unroll
        for (int j = 0; j < 4; ++j) v[j] = acc[i][j] + bv[j];
        if (gc0 < 128){
          float4 o; o.x = silu_f(v[0]); o.y = silu_f(v[1]); o.z = silu_f(v[2]); o.w = silu_f(v[3]);
          *(float4*)&g_za[tok*128 + gc0] = o;
        } else if (gc0 < 256){
          float4 o; o.x = silu_f(v[0]); o.y = silu_f(v[1]); o.z = silu_f(v[2]); o.w = silu_f(v[3]);
          *(float4*)&g_xy[tok*128 + gc0 - 128] = o;
        } else if (gc0 < 288){
          float4 o; o.x = silu_f(v[0]); o.y = silu_f(v[1]); o.z = silu_f(v[2]); o.w = silu_f(v[3]);
          *(float4*)&g_Ba[tok*32 + gc0 - 256] = o;
        } else if (gc0 < 320){
          float4 o; o.x = silu_f(v[0]); o.y = silu_f(v[1]); o.z = silu_f(v[2]); o.w = silu_f(v[3]);
          *(float4*)&g_Ca[tok*32 + gc0 - 288] = o;
        } else {
          float4 o;
          o.x = softplus_f(v[0] + dt_bias[l*4 + 0]);
          o.y = softplus_f(v[1] + dt_bias[l*4 + 1]);
          o.z = softplus_f(v[2] + dt_bias[l*4 + 2]);
          o.w = softplus_f(v[3] + dt_bias[l*4 + 3]);
          *(float4*)&g_dt[tok*4] = o;
        }
      }
    }
  }
}

// ---------------- chunk intra: G, M, y_intra + D*x (in-place over xa), chunk state ----------------
__global__ __launch_bounds__(256) void k_s1(
    const float* __restrict__ A_log, const float* __restrict__ Dp, int l)
{
  __shared__ float Bs[64*37];
  __shared__ float Cs[64*37];
  __shared__ float Gl[64*65];
  __shared__ float Ml[64*65];
  __shared__ float Xh[64*36];
  __shared__ float dtl[4*64];
  __shared__ float Sl[4*64];
  __shared__ float wl[4*64];
  const int tid = threadIdx.x;
  const int cI = blockIdx.x, b = blockIdx.y;
  const long tb = (long)b*LSEQ + (long)cI*QC;
  for (int i = tid; i < 2048; i += 256){
    int s = i >> 5, n = i & 31;
    Bs[s*37 + n] = g_Ba[(tb + s)*32 + n];
    Cs[s*37 + n] = g_Ca[(tb + s)*32 + n];
  }
  { int t = tid >> 2, h = tid & 3; dtl[h*64 + t] = g_dt[(tb + t)*4 + h]; }
  __syncthreads();
  if (tid < 4){
    const int h = tid;
    const float Ah = -__expf(A_log[l*4 + h]);
    float run = 0.f;
    for (int t = 0; t < 64; ++t){ run += dtl[h*64 + t] * Ah; Sl[h*64 + t] = run; }
    const float Send = run;
    for (int t = 0; t < 64; ++t) wl[h*64 + t] = __expf(Send - Sl[h*64 + t]) * dtl[h*64 + t];
    g_cL[((long)b*NCH + cI)*4 + h] = Send;
  }
  __syncthreads();
  { int t = tid >> 2, h = tid & 3; g_pc[(tb + t)*4 + h] = __expf(Sl[h*64 + t]); }
  const int t0 = (tid >> 4) * 4, s0 = (tid & 15) * 4;
  if (s0 <= t0 + 3){
    float acc[4][4];
    #pragma unroll
    for (int i = 0; i < 4; ++i)
      #pragma unroll
      for (int j = 0; j < 4; ++j) acc[i][j] = 0.f;
    for (int n = 0; n < 32; ++n){
      float bva[4], cva[4];
      #pragma unroll
      for (int j = 0; j < 4; ++j) bva[j] = Bs[(s0+j)*37 + n];
      #pragma unroll
      for (int i = 0; i < 4; ++i) cva[i] = Cs[(t0+i)*37 + n];
      #pragma unroll
      for (int i = 0; i < 4; ++i)
        #pragma unroll
        for (int j = 0; j < 4; ++j) acc[i][j] += cva[i] * bva[j];
    }
    #pragma unroll
    for (int i = 0; i < 4; ++i)
      #pragma unroll
      for (int j = 0; j < 4; ++j) Gl[(t0+i)*65 + s0 + j] = acc[i][j];
  }
  for (int h = 0; h < NHD; ++h){
    __syncthreads();   // Gl ready (h=0) / prior head done with Ml,Xh
    for (int i = tid; i < 2048; i += 256){
      int s = i >> 5, p = i & 31;
      Xh[s*36 + p] = g_xy[(tb + s)*128 + h*32 + p];
    }
    {
      float m[4][4];
      #pragma unroll
      for (int i = 0; i < 4; ++i)
        #pragma unroll
        for (int j = 0; j < 4; ++j){
          const int t = t0 + i, s = s0 + j;
          m[i][j] = (s <= t) ? __expf(Sl[h*64 + t] - Sl[h*64 + s]) * dtl[h*64 + s] * Gl[t*65 + s]
                             : 0.f;
        }
      #pragma unroll
      for (int i = 0; i < 4; ++i)
        #pragma unroll
        for (int j = 0; j < 4; ++j) Ml[(t0+i)*65 + s0 + j] = m[i][j];
    }
    __syncthreads();
    const float Dh = Dp[l*4 + h];
    { // y_intra (+ D*x) written IN PLACE over xa (same token range, LDS already holds x)
      const int p0 = (tid & 7) * 4;
      const int tt0 = (tid >> 3) * 2;
      float a0[4] = {0,0,0,0}, a1[4] = {0,0,0,0};
      for (int s = 0; s < 64; ++s){
        const float m0 = Ml[tt0*65 + s];
        const float m1 = Ml[(tt0+1)*65 + s];
        float4 x4 = *(const float4*)&Xh[s*36 + p0];
        float xv[4] = {x4.x, x4.y, x4.z, x4.w};
        #pragma unroll
        for (int j = 0; j < 4; ++j){ a0[j] += m0 * xv[j]; a1[j] += m1 * xv[j]; }
      }
      float4 xt0 = *(const float4*)&Xh[tt0*36 + p0];
      float4 xt1 = *(const float4*)&Xh[(tt0+1)*36 + p0];
      float4 o0, o1;
      o0.x = a0[0] + Dh*xt0.x; o0.y = a0[1] + Dh*xt0.y; o0.z = a0[2] + Dh*xt0.z; o0.w = a0[3] + Dh*xt0.w;
      o1.x = a1[0] + Dh*xt1.x; o1.y = a1[1] + Dh*xt1.y; o1.z = a1[2] + Dh*xt1.z; o1.w = a1[3] + Dh*xt1.w;
      *(float4*)&g_xy[(tb + tt0    )*128 + h*32 + p0] = o0;
      *(float4*)&g_xy[(tb + tt0 + 1)*128 + h*32 + p0] = o1;
    }
    { // chunkS[p][n] = sum_s wl[s] * X[s][p] * B[s][n]
      const int p = tid >> 3;
      const int n0 = (tid & 7) * 4;
      float acc[4] = {0,0,0,0};
      for (int s = 0; s < 64; ++s){
        const float wx = wl[h*64 + s] * Xh[s*36 + p];
        #pragma unroll
        for (int j = 0; j < 4; ++j) acc[j] += wx * Bs[s*37 + n0 + j];
      }
      float4 o; o.x = acc[0]; o.y = acc[1]; o.z = acc[2]; o.w = acc[3];
      *(float4*)&g_cS[(((long)b*NCH + cI)*NHD + h)*(HDD*DSD) + p*32 + n0] = o;
    }
  }
}

// ---------------- cross-chunk state prefix scan (in place: cS -> H_in) ----------------
__global__ __launch_bounds__(1024) void k_s2()
{
  const int h = blockIdx.x, b = blockIdx.y;
  const int tid = threadIdx.x;
  float H = 0.f;
  for (int c = 0; c < NCH; ++c){
    const long o = (((long)b*NCH + c)*NHD + h)*1024 + tid;
    const float cs = g_cS[o];                 // read BEFORE overwrite (in-place scan)
    const float lg = g_cL[((long)b*NCH + c)*4 + h];
    g_cS[o] = H;
    H = __expf(lg) * H + cs;
  }
}

// ---------------- y_inter + gate + out_proj + residual ----------------
__global__ __launch_bounds__(256) void k_s3(
    const float* __restrict__ Wo, const float* __restrict__ bo, int l)
{
  __shared__ float Hl[128*33];
  __shared__ float Cl[64*36];
  __shared__ float pcl[4*64];
  __shared__ float gl[64*132];
  const int tid = threadIdx.x;
  const int cI = blockIdx.x, b = blockIdx.y;
  const long tb = (long)b*LSEQ + (long)cI*QC;
  const long hb = (((long)b*NCH + cI)*NHD)*(long)(HDD*DSD);
  for (int i = tid; i < 4096; i += 256) Hl[(i>>5)*33 + (i&31)] = g_cS[hb + i];
  for (int i = tid; i < 2048; i += 256){
    int t = i >> 5, n = i & 31;
    Cl[t*36 + n] = g_Ca[(tb + t)*32 + n];
  }
  { int t = tid >> 2, h = tid & 3; pcl[h*64 + t] = g_pc[(tb + t)*4 + h]; }
  __syncthreads();
  const int t0 = (tid >> 4) * 4;
  const int q = tid & 15;
  float acc[4][8];
  #pragma unroll
  for (int i = 0; i < 4; ++i)
    #pragma unroll
    for (int j = 0; j < 8; ++j) acc[i][j] = 0.f;
  for (int n = 0; n < 32; ++n){
    float cv[4], hv[8];
    #pragma unroll
    for (int i = 0; i < 4; ++i) cv[i] = Cl[(t0+i)*36 + n];
    #pragma unroll
    for (int j = 0; j < 8; ++j) hv[j] = Hl[(q + 16*j)*33 + n];
    #pragma unroll
    for (int i = 0; i < 4; ++i)
      #pragma unroll
      for (int j = 0; j < 8; ++j) acc[i][j] += cv[i] * hv[j];
  }
  #pragma unroll
  for (int i = 0; i < 4; ++i){
    const long tok = tb + t0 + i;
    #pragma unroll
    for (int j = 0; j < 8; ++j){
      const int hp = q + 16*j;
      const int h = hp >> 5;
      const float v = pcl[h*64 + t0 + i] * acc[i][j] + g_xy[tok*128 + hp];
      gl[(t0+i)*132 + hp] = v * silu_f(g_za[tok*128 + hp]);
    }
  }
  __syncthreads();
  const int dm0 = (tid & 15) * 4;
  const float* Wol = Wo + (long)l * 128 * 64;
  float a2[4][4];
  #pragma unroll
  for (int i = 0; i < 4; ++i)
    #pragma unroll
    for (int j = 0; j < 4; ++j) a2[i][j] = 0.f;
  for (int kk = 0; kk < 128; ++kk){
    float4 w4 = *(const float4*)&Wol[kk*64 + dm0];
    float wv[4] = {w4.x, w4.y, w4.z, w4.w};
    #pragma unroll
    for (int ii = 0; ii < 4; ++ii){
      const float gv = gl[(t0+ii)*132 + kk];
      #pragma unroll
      for (int j = 0; j < 4; ++j) a2[ii][j] += gv * wv[j];
    }
  }
  float4 b4 = *(const float4*)&bo[l*64 + dm0];
  float bv[4] = {b4.x, b4.y, b4.z, b4.w};
  #pragma unroll
  for (int ii = 0; ii < 4; ++ii){
    const long tok = tb + t0 + ii;
    float4 h4 = *(const float4*)&g_h0[tok*64 + dm0];
    float hv[4] = {h4.x, h4.y, h4.z, h4.w};
    float4 o;
    o.x = a2[ii][0] + bv[0] + hv[0];
    o.y = a2[ii][1] + bv[1] + hv[1];
    o.z = a2[ii][2] + bv[2] + hv[2];
    o.w = a2[ii][3] + bv[3] + hv[3];
    *(float4*)&g_h0[tok*64 + dm0] = o;
  }
}

// ---------------- pooling + classifier ----------------
__global__ __launch_bounds__(256) void k_pool1()
{
  __shared__ float red[4*64];
  const int tid = threadIdx.x;
  const int cch = blockIdx.x, b = blockIdx.y;
  const int dm = tid & 63, g = tid >> 6;
  double acc = 0.0;
  const long base = ((long)b*LSEQ + cch*512 + g*128)*64 + dm;
  for (int i = 0; i < 128; ++i) acc += (double)g_h0[base + (long)i*64];
  red[g*64 + dm] = (float)acc;
  __syncthreads();
  if (g == 0){
    float s = red[dm] + red[64 + dm] + red[128 + dm] + red[192 + dm];
    g_pp[((long)b*16 + cch)*64 + dm] = s;
  }
}

__global__ __launch_bounds__(64) void k_pool2(
    const float* __restrict__ cW, const float* __restrict__ cb,
    float* __restrict__ out)
{
  __shared__ float pl[64];
  const int b = blockIdx.x, tid = threadIdx.x;
  float s = 0.f;
  for (int c = 0; c < 16; ++c) s += g_pp[((long)b*16 + c)*64 + tid];
  pl[tid] = s * (1.0f / 8192.0f);
  __syncthreads();
  if (tid < NOUTC){
    float acc = cb[tid];
    for (int dm = 0; dm < 64; ++dm) acc += pl[dm] * cW[dm*NOUTC + tid];
    out[b*NOUTC + tid] = acc;
  }
}

extern "C" void kernel_launch(void* const* d_in, const int* in_sizes, int n_in,
                              void* d_out, int out_size, void* d_ws, size_t ws_size,
                              hipStream_t stream)
{
  const float* x      = (const float*)d_in[0];
  const float* W_in   = (const float*)d_in[1];
  const float* b_in   = (const float*)d_in[2];
  const float* ipW    = (const float*)d_in[3];
  const float* ipb    = (const float*)d_in[4];
  const float* A_log  = (const float*)d_in[5];
  const float* Dp     = (const float*)d_in[6];
  const float* dtb    = (const float*)d_in[7];
  const float* opW    = (const float*)d_in[8];
  const float* opb    = (const float*)d_in[9];
  const float* clsW   = (const float*)d_in[10];
  const float* clsb   = (const float*)d_in[11];
  float* out = (float*)d_out;
  (void)d_ws; (void)ws_size;

  k_linin<<<2048, 256, 0, stream>>>(x, W_in, b_in);
  for (int l = 0; l < NLAY; ++l){
    k_proj<<<2048, 256, 0, stream>>>(ipW, ipb, dtb, l);
    k_s1<<<dim3(NCH, BSZ), 256, 0, stream>>>(A_log, Dp, l);
    k_s2<<<dim3(NHD, BSZ), 1024, 0, stream>>>();
    k_s3<<<dim3(NCH, BSZ), 256, 0, stream>>>(opW, opb, l);
  }
  k_pool1<<<dim3(16, BSZ), 256, 0, stream>>>();
  k_pool2<<<BSZ, 64, 0, stream>>>(clsW, clsb, out);
}

// Round 3
// 771.286 us; speedup vs baseline: 1.1160x; 1.1160x over previous
//
#include <hip/hip_runtime.h>

#define BSZ   16
#define LSEQ  8192
#define DMDL  64
#define DSD   32
#define HDD   32
#define NHD   4
#define DIN   128
#define NLAY  2
#define NOUTC 6
#define DPRJ  324
#define QC    64
#define NCH   128   // LSEQ/QC

// ---- device-global scratch ----
__device__ float g_h0[BSZ*LSEQ*DMDL];
__device__ float g_za[BSZ*LSEQ*DIN];
__device__ float g_xy[BSZ*LSEQ*DIN];        // x, overwritten in-place by y_intra
__device__ float g_Ba[BSZ*LSEQ*DSD];
__device__ float g_Ca[BSZ*LSEQ*DSD];
__device__ float g_dt[BSZ*LSEQ*NHD];
__device__ float g_pc[BSZ*LSEQ*NHD];
__device__ float g_cS[BSZ*NCH*NHD*HDD*DSD]; // chunk states, scanned in-place -> H_in
__device__ float g_cL[BSZ*NCH*NHD];
__device__ float g_pp[BSZ*16*DMDL];

__device__ __forceinline__ float silu_f(float v){ return v / (1.0f + __expf(-v)); }
__device__ __forceinline__ float softplus_f(float v){ return (v > 15.0f) ? v : __logf(1.0f + __expf(v)); }

// ---------------- linear_in ----------------
__global__ __launch_bounds__(256) void k_linin(
    const float* __restrict__ x, const float* __restrict__ W,
    const float* __restrict__ bias)
{
  __shared__ float xs[64*60];
  __shared__ float wl[57*64];
  const int tid = threadIdx.x;
  const long tb = (long)blockIdx.x * 64;
  for (int i = tid; i < 64*57; i += 256){
    int t = i / 57, k = i - t*57;
    xs[t*60 + k] = x[tb*57 + i];
  }
  for (int i = tid; i < 57*64; i += 256) wl[i] = W[i];
  __syncthreads();
  const int t0 = (tid >> 4) * 4, d0 = (tid & 15) * 4;
  float acc[4][4];
  #pragma unroll
  for (int i = 0; i < 4; ++i)
    #pragma unroll
    for (int j = 0; j < 4; ++j) acc[i][j] = 0.f;
  for (int k = 0; k < 57; ++k){
    float4 w4 = *(const float4*)&wl[k*64 + d0];
    float wv[4] = {w4.x, w4.y, w4.z, w4.w};
    #pragma unroll
    for (int i = 0; i < 4; ++i){
      float xv = xs[(t0+i)*60 + k];
      #pragma unroll
      for (int j = 0; j < 4; ++j) acc[i][j] += xv * wv[j];
    }
  }
  float4 b4 = *(const float4*)&bias[d0];
  float bv[4] = {b4.x, b4.y, b4.z, b4.w};
  #pragma unroll
  for (int i = 0; i < 4; ++i){
    float4 o;
    o.x = acc[i][0] + bv[0]; o.y = acc[i][1] + bv[1];
    o.z = acc[i][2] + bv[2]; o.w = acc[i][3] + bv[3];
    *(float4*)&g_h0[(tb + t0 + i)*64 + d0] = o;
  }
}

// ---------------- in_proj GEMM + activations (128 tokens/block) ----------------
__global__ __launch_bounds__(256) void k_proj(
    const float* __restrict__ W, const float* __restrict__ bias,
    const float* __restrict__ dt_bias, int l)
{
  __shared__ float hst[64*132];  // [k][t] transposed, 128 tokens, pad 132 (16B-aligned rows)
  __shared__ float Wt[64*68];    // [k][c]
  const int tid = threadIdx.x;
  const long tb = (long)blockIdx.x * 128;
  for (int i = tid; i < 8192; i += 256){
    int t = i >> 6, k = i & 63;
    hst[k*132 + t] = g_h0[(tb + t)*64 + k];
  }
  const float* Wl = W + (long)l * 64 * DPRJ;
  const float* bl = bias + (long)l * DPRJ;
  const int t0 = (tid >> 4) * 8, c0 = (tid & 15) * 4;
  for (int ct = 0; ct < 6; ++ct){
    const int cbase = ct * 64;
    const int cw = (ct == 5) ? 4 : 64;
    __syncthreads();
    for (int i = tid; i < 64 * cw; i += 256){
      int k = i / cw, cc = i - k * cw;
      Wt[k*68 + cc] = Wl[k*DPRJ + cbase + cc];
    }
    __syncthreads();
    if (c0 < cw){
      float acc[8][4];
      #pragma unroll
      for (int i = 0; i < 8; ++i)
        #pragma unroll
        for (int j = 0; j < 4; ++j) acc[i][j] = 0.f;
      for (int k = 0; k < 64; ++k){
        float4 w4 = *(const float4*)&Wt[k*68 + c0];
        float4 ha = *(const float4*)&hst[k*132 + t0];
        float4 hb = *(const float4*)&hst[k*132 + t0 + 4];
        float wv[4] = {w4.x, w4.y, w4.z, w4.w};
        float hv[8] = {ha.x, ha.y, ha.z, ha.w, hb.x, hb.y, hb.z, hb.w};
        #pragma unroll
        for (int i = 0; i < 8; ++i)
          #pragma unroll
          for (int j = 0; j < 4; ++j) acc[i][j] += hv[i] * wv[j];
      }
      const int gc0 = cbase + c0;
      float bv[4] = {bl[gc0], bl[gc0+1], bl[gc0+2], bl[gc0+3]};
      #pragma unroll
      for (int i = 0; i < 8; ++i){
        const long tok = tb + t0 + i;
        float v[4];
        #pragma unroll
        for (int j = 0; j < 4; ++j) v[j] = acc[i][j] + bv[j];
        if (gc0 < 128){
          float4 o; o.x = silu_f(v[0]); o.y = silu_f(v[1]); o.z = silu_f(v[2]); o.w = silu_f(v[3]);
          *(float4*)&g_za[tok*128 + gc0] = o;
        } else if (gc0 < 256){
          float4 o; o.x = silu_f(v[0]); o.y = silu_f(v[1]); o.z = silu_f(v[2]); o.w = silu_f(v[3]);
          *(float4*)&g_xy[tok*128 + gc0 - 128] = o;
        } else if (gc0 < 288){
          float4 o; o.x = silu_f(v[0]); o.y = silu_f(v[1]); o.z = silu_f(v[2]); o.w = silu_f(v[3]);
          *(float4*)&g_Ba[tok*32 + gc0 - 256] = o;
        } else if (gc0 < 320){
          float4 o; o.x = silu_f(v[0]); o.y = silu_f(v[1]); o.z = silu_f(v[2]); o.w = silu_f(v[3]);
          *(float4*)&g_Ca[tok*32 + gc0 - 288] = o;
        } else {
          float4 o;
          o.x = softplus_f(v[0] + dt_bias[l*4 + 0]);
          o.y = softplus_f(v[1] + dt_bias[l*4 + 1]);
          o.z = softplus_f(v[2] + dt_bias[l*4 + 2]);
          o.w = softplus_f(v[3] + dt_bias[l*4 + 3]);
          *(float4*)&g_dt[tok*4] = o;
        }
      }
    }
  }
}

// ---------------- chunk intra (no Ml materialization; block-factorized decay) ----------------
__global__ __launch_bounds__(256) void k_s1(
    const float* __restrict__ A_log, const float* __restrict__ Dp, int l)
{
  __shared__ float Bs[64*37];
  __shared__ float Cs[64*37];
  __shared__ float Gl[64*65];
  __shared__ float Xh[64*36];
  __shared__ float dtl[4*64];
  __shared__ float Sl[4*64];
  __shared__ float wl[4*64];
  __shared__ float carr[4*64];   // exp(R_b(s) - Sl[s]) * dt[s]
  __shared__ float earr[4*4*64]; // [h][beta][t]: exp(Sl[t]-R_beta), 0 if t<16*beta
  __shared__ float Send[4], Rb[4*4];
  const int tid = threadIdx.x;
  const int cI = blockIdx.x, b = blockIdx.y;
  const long tb = (long)b*LSEQ + (long)cI*QC;
  for (int i = tid; i < 2048; i += 256){
    int s = i >> 5, n = i & 31;
    Bs[s*37 + n] = g_Ba[(tb + s)*32 + n];
    Cs[s*37 + n] = g_Ca[(tb + s)*32 + n];
  }
  { int t = tid >> 2, h = tid & 3; dtl[h*64 + t] = g_dt[(tb + t)*4 + h]; }
  __syncthreads();
  if (tid < 4){
    const int h = tid;
    const float Ah = -__expf(A_log[l*4 + h]);
    float run = 0.f;
    for (int t = 0; t < 64; ++t){
      if ((t & 15) == 0) Rb[h*4 + (t>>4)] = run;   // exclusive prefix at block start
      run += dtl[h*64 + t] * Ah;
      Sl[h*64 + t] = run;
    }
    Send[h] = run;
    g_cL[((long)b*NCH + cI)*4 + h] = run;
  }
  __syncthreads();
  { // transcendentals in parallel (256 = 4h x 64s)
    const int h = tid >> 6, s = tid & 63;
    const float sl = Sl[h*64 + s];
    wl[h*64 + s]   = __expf(Send[h] - sl) * dtl[h*64 + s];
    carr[h*64 + s] = __expf(Rb[h*4 + (s>>4)] - sl) * dtl[h*64 + s];
  }
  { int t = tid >> 2, h = tid & 3; g_pc[(tb + t)*4 + h] = __expf(Sl[h*64 + t]); }
  for (int i = tid; i < 1024; i += 256){
    const int h = i >> 8, bb = (i >> 6) & 3, t = i & 63;
    earr[i] = (t >= bb*16) ? __expf(Sl[h*64 + t] - Rb[h*4 + bb]) : 0.f;
  }
  __syncthreads();
  // G[t][s] = B_s . C_t (lower-triangle-touching tiles only)
  const int t0 = (tid >> 4) * 4, s0 = (tid & 15) * 4;
  if (s0 <= t0 + 3){
    float acc[4][4];
    #pragma unroll
    for (int i = 0; i < 4; ++i)
      #pragma unroll
      for (int j = 0; j < 4; ++j) acc[i][j] = 0.f;
    for (int n = 0; n < 32; ++n){
      float bva[4], cva[4];
      #pragma unroll
      for (int j = 0; j < 4; ++j) bva[j] = Bs[(s0+j)*37 + n];
      #pragma unroll
      for (int i = 0; i < 4; ++i) cva[i] = Cs[(t0+i)*37 + n];
      #pragma unroll
      for (int i = 0; i < 4; ++i)
        #pragma unroll
        for (int j = 0; j < 4; ++j) acc[i][j] += cva[i] * bva[j];
    }
    #pragma unroll
    for (int i = 0; i < 4; ++i)
      #pragma unroll
      for (int j = 0; j < 4; ++j) Gl[(t0+i)*65 + s0 + j] = acc[i][j];
  }
  const int tt0 = (tid >> 3) * 2;      // rows for y_intra
  const int p0g = (tid & 7) * 4;
  const int tblk = tt0 >> 4;           // wave-uniform
  for (int h = 0; h < NHD; ++h){
    __syncthreads();   // Gl ready (h=0) / prior head done with Xh
    for (int i = tid; i < 2048; i += 256){
      int s = i >> 5, p = i & 31;
      Xh[s*36 + p] = g_xy[(tb + s)*128 + h*32 + p];
    }
    __syncthreads();
    const float Dh = Dp[l*4 + h];
    { // y_intra: M[t][s] = e[beta][t]*c[s]*G[t][s], s<=t
      float a0[4] = {0,0,0,0}, a1[4] = {0,0,0,0};
      for (int bb = 0; bb <= tblk; ++bb){
        const float e0 = earr[(h*4 + bb)*64 + tt0];
        const float e1 = earr[(h*4 + bb)*64 + tt0 + 1];
        const int sbase = bb * 16;
        if (bb < tblk){
          #pragma unroll
          for (int ss = 0; ss < 16; ++ss){
            const int s = sbase + ss;
            const float c = carr[h*64 + s];
            const float m0 = e0 * c * Gl[tt0*65 + s];
            const float m1 = e1 * c * Gl[(tt0+1)*65 + s];
            float4 x4 = *(const float4*)&Xh[s*36 + p0g];
            float xv[4] = {x4.x, x4.y, x4.z, x4.w};
            #pragma unroll
            for (int j = 0; j < 4; ++j){ a0[j] += m0 * xv[j]; a1[j] += m1 * xv[j]; }
          }
        } else {
          #pragma unroll
          for (int ss = 0; ss < 16; ++ss){
            const int s = sbase + ss;
            const float c = carr[h*64 + s];
            const float m0 = (s <= tt0    ) ? e0 * c * Gl[tt0*65 + s]     : 0.f;
            const float m1 = (s <= tt0 + 1) ? e1 * c * Gl[(tt0+1)*65 + s] : 0.f;
            float4 x4 = *(const float4*)&Xh[s*36 + p0g];
            float xv[4] = {x4.x, x4.y, x4.z, x4.w};
            #pragma unroll
            for (int j = 0; j < 4; ++j){ a0[j] += m0 * xv[j]; a1[j] += m1 * xv[j]; }
          }
        }
      }
      float4 xt0 = *(const float4*)&Xh[tt0*36 + p0g];
      float4 xt1 = *(const float4*)&Xh[(tt0+1)*36 + p0g];
      float4 o0, o1;
      o0.x = a0[0] + Dh*xt0.x; o0.y = a0[1] + Dh*xt0.y; o0.z = a0[2] + Dh*xt0.z; o0.w = a0[3] + Dh*xt0.w;
      o1.x = a1[0] + Dh*xt1.x; o1.y = a1[1] + Dh*xt1.y; o1.z = a1[2] + Dh*xt1.z; o1.w = a1[3] + Dh*xt1.w;
      *(float4*)&g_xy[(tb + tt0    )*128 + h*32 + p0g] = o0;
      *(float4*)&g_xy[(tb + tt0 + 1)*128 + h*32 + p0g] = o1;
    }
    { // chunkS[p][n] = sum_s wl[s] * X[s][p] * B[s][n]
      const int p = tid >> 3;
      const int n0 = (tid & 7) * 4;
      float acc[4] = {0,0,0,0};
      for (int s = 0; s < 64; ++s){
        const float wx = wl[h*64 + s] * Xh[s*36 + p];
        #pragma unroll
        for (int j = 0; j < 4; ++j) acc[j] += wx * Bs[s*37 + n0 + j];
      }
      float4 o; o.x = acc[0]; o.y = acc[1]; o.z = acc[2]; o.w = acc[3];
      *(float4*)&g_cS[(((long)b*NCH + cI)*NHD + h)*(HDD*DSD) + p*32 + n0] = o;
    }
  }
}

// ---------------- cross-chunk state prefix scan (in place), 512 blocks ----------------
__global__ __launch_bounds__(128) void k_s2()
{
  const int h = blockIdx.x >> 3, seg = blockIdx.x & 7, b = blockIdx.y;
  const int idx = seg*128 + threadIdx.x;
  float H = 0.f;
  for (int c = 0; c < NCH; ++c){
    const long o = (((long)b*NCH + c)*NHD + h)*1024 + idx;
    const float cs = g_cS[o];
    const float lg = g_cL[((long)b*NCH + c)*4 + h];
    g_cS[o] = H;
    H = __expf(lg) * H + cs;
  }
}

// ---------------- y_inter + gate + out_proj (two k-halves) + residual ----------------
__global__ __launch_bounds__(256) void k_s3(
    const float* __restrict__ Wo, const float* __restrict__ bo, int l)
{
  __shared__ float Hl[128*33];
  __shared__ float Cl[64*36];
  __shared__ float pcl[4*64];
  __shared__ float gl[64*68];   // half of the gated matrix at a time
  const int tid = threadIdx.x;
  const int cI = blockIdx.x, b = blockIdx.y;
  const long tb = (long)b*LSEQ + (long)cI*QC;
  const long hb = (((long)b*NCH + cI)*NHD)*(long)(HDD*DSD);
  for (int i = tid; i < 4096; i += 256) Hl[(i>>5)*33 + (i&31)] = g_cS[hb + i];
  for (int i = tid; i < 2048; i += 256){
    int t = i >> 5, n = i & 31;
    Cl[t*36 + n] = g_Ca[(tb + t)*32 + n];
  }
  { int t = tid >> 2, h = tid & 3; pcl[h*64 + t] = g_pc[(tb + t)*4 + h]; }
  __syncthreads();
  const int t0 = (tid >> 4) * 4;
  const int q = tid & 15;
  float acc[4][8];
  #pragma unroll
  for (int i = 0; i < 4; ++i)
    #pragma unroll
    for (int j = 0; j < 8; ++j) acc[i][j] = 0.f;
  for (int n = 0; n < 32; ++n){
    float cv[4], hv[8];
    #pragma unroll
    for (int i = 0; i < 4; ++i) cv[i] = Cl[(t0+i)*36 + n];
    #pragma unroll
    for (int j = 0; j < 8; ++j) hv[j] = Hl[(q + 16*j)*33 + n];
    #pragma unroll
    for (int i = 0; i < 4; ++i)
      #pragma unroll
      for (int j = 0; j < 8; ++j) acc[i][j] += cv[i] * hv[j];
  }
  float yg[4][8];
  #pragma unroll
  for (int i = 0; i < 4; ++i){
    const long tok = tb + t0 + i;
    #pragma unroll
    for (int j = 0; j < 8; ++j){
      const int hp = q + 16*j;
      const int h = hp >> 5;
      const float v = pcl[h*64 + t0 + i] * acc[i][j] + g_xy[tok*128 + hp];
      yg[i][j] = v * silu_f(g_za[tok*128 + hp]);
    }
  }
  const int dm0 = (tid & 15) * 4;
  const float* Wol = Wo + (long)l * 128 * 64;
  float a2[4][4];
  #pragma unroll
  for (int i = 0; i < 4; ++i)
    #pragma unroll
    for (int j = 0; j < 4; ++j) a2[i][j] = 0.f;
  #pragma unroll
  for (int half = 0; half < 2; ++half){
    __syncthreads();
    #pragma unroll
    for (int i = 0; i < 4; ++i)
      #pragma unroll
      for (int j = 0; j < 4; ++j){
        const int hp = q + 16*(j + 4*half);
        gl[(t0+i)*68 + (hp - 64*half)] = yg[i][j + 4*half];
      }
    __syncthreads();
    for (int kk = 0; kk < 64; ++kk){
      float4 w4 = *(const float4*)&Wol[(kk + 64*half)*64 + dm0];
      float wv[4] = {w4.x, w4.y, w4.z, w4.w};
      #pragma unroll
      for (int ii = 0; ii < 4; ++ii){
        const float gv = gl[(t0+ii)*68 + kk];
        #pragma unroll
        for (int j = 0; j < 4; ++j) a2[ii][j] += gv * wv[j];
      }
    }
  }
  float4 b4 = *(const float4*)&bo[l*64 + dm0];
  float bv[4] = {b4.x, b4.y, b4.z, b4.w};
  #pragma unroll
  for (int ii = 0; ii < 4; ++ii){
    const long tok = tb + t0 + ii;
    float4 h4 = *(const float4*)&g_h0[tok*64 + dm0];
    float hv[4] = {h4.x, h4.y, h4.z, h4.w};
    float4 o;
    o.x = a2[ii][0] + bv[0] + hv[0];
    o.y = a2[ii][1] + bv[1] + hv[1];
    o.z = a2[ii][2] + bv[2] + hv[2];
    o.w = a2[ii][3] + bv[3] + hv[3];
    *(float4*)&g_h0[tok*64 + dm0] = o;
  }
}

// ---------------- pooling + classifier ----------------
__global__ __launch_bounds__(256) void k_pool1()
{
  __shared__ float red[4*64];
  const int tid = threadIdx.x;
  const int cch = blockIdx.x, b = blockIdx.y;
  const int dm = tid & 63, g = tid >> 6;
  double acc = 0.0;
  const long base = ((long)b*LSEQ + cch*512 + g*128)*64 + dm;
  for (int i = 0; i < 128; ++i) acc += (double)g_h0[base + (long)i*64];
  red[g*64 + dm] = (float)acc;
  __syncthreads();
  if (g == 0){
    float s = red[dm] + red[64 + dm] + red[128 + dm] + red[192 + dm];
    g_pp[((long)b*16 + cch)*64 + dm] = s;
  }
}

__global__ __launch_bounds__(64) void k_pool2(
    const float* __restrict__ cW, const float* __restrict__ cb,
    float* __restrict__ out)
{
  __shared__ float pl[64];
  const int b = blockIdx.x, tid = threadIdx.x;
  float s = 0.f;
  for (int c = 0; c < 16; ++c) s += g_pp[((long)b*16 + c)*64 + tid];
  pl[tid] = s * (1.0f / 8192.0f);
  __syncthreads();
  if (tid < NOUTC){
    float acc = cb[tid];
    for (int dm = 0; dm < 64; ++dm) acc += pl[dm] * cW[dm*NOUTC + tid];
    out[b*NOUTC + tid] = acc;
  }
}

extern "C" void kernel_launch(void* const* d_in, const int* in_sizes, int n_in,
                              void* d_out, int out_size, void* d_ws, size_t ws_size,
                              hipStream_t stream)
{
  const float* x      = (const float*)d_in[0];
  const float* W_in   = (const float*)d_in[1];
  const float* b_in   = (const float*)d_in[2];
  const float* ipW    = (const float*)d_in[3];
  const float* ipb    = (const float*)d_in[4];
  const float* A_log  = (const float*)d_in[5];
  const float* Dp     = (const float*)d_in[6];
  const float* dtb    = (const float*)d_in[7];
  const float* opW    = (const float*)d_in[8];
  const float* opb    = (const float*)d_in[9];
  const float* clsW   = (const float*)d_in[10];
  const float* clsb   = (const float*)d_in[11];
  float* out = (float*)d_out;
  (void)d_ws; (void)ws_size;

  k_linin<<<2048, 256, 0, stream>>>(x, W_in, b_in);
  for (int l = 0; l < NLAY; ++l){
    k_proj<<<1024, 256, 0, stream>>>(ipW, ipb, dtb, l);
    k_s1<<<dim3(NCH, BSZ), 256, 0, stream>>>(A_log, Dp, l);
    k_s2<<<dim3(32, BSZ), 128, 0, stream>>>();
    k_s3<<<dim3(NCH, BSZ), 256, 0, stream>>>(opW, opb, l);
  }
  k_pool1<<<dim3(16, BSZ), 256, 0, stream>>>();
  k_pool2<<<BSZ, 64, 0, stream>>>(clsW, clsb, out);
}